// Round 2
// baseline (1039.296 us; speedup 1.0000x reference)
//
#include <hip/hip_runtime.h>

// NodeEdgeProjection: out[b, e, f] = in[b, e/127, f]
//   B=256, N=128 nodes, E=128*127=16256 edges, F=64 features, fp32.
// EDGE_RECEIVER[e] == e // 127 (lexicographic permutations, first column),
// so this is a pure broadcast: each 64-float node row replicated 127x.
// Write-bandwidth bound: 1.065 GB out, 8 MB in.

// Native clang vector type: __builtin_nontemporal_store rejects HIP's
// float4 class, but accepts ext_vector_type.
typedef float vfloat4 __attribute__((ext_vector_type(4)));

#define NNODES   128
#define DEG      127            // edges per receiving node (N-1)
#define FEAT4    16             // 64 floats = 16 vfloat4 per row
#define CHUNK4   (DEG * FEAT4)  // 2032 vfloat4 per (b,node) output chunk
#define BLOCK    256

__global__ __launch_bounds__(BLOCK)
void NodeEdgeProjection_5025111736904_kernel(const vfloat4* __restrict__ in,
                                             vfloat4* __restrict__ out) {
    const int t   = threadIdx.x;
    const int blk = blockIdx.x;               // blk = b*128 + node

    // Each thread's output slots p = t + k*256 all satisfy p % 16 == t % 16,
    // so it needs exactly one vfloat4 of the source row (L1/L2-broadcast read).
    const vfloat4 v = in[(size_t)blk * FEAT4 + (t & (FEAT4 - 1))];

    // Output chunk for (b,node) is contiguous: ((b*16256) + node*127)*64
    // floats == blk * 2032 vfloat4.
    vfloat4* __restrict__ dst = out + (size_t)blk * CHUNK4;

#pragma unroll
    for (int k = 0; k < 8; ++k) {             // 2032 = 7*256 + 240
        const int p = t + k * BLOCK;
        if (p < CHUNK4) {
            __builtin_nontemporal_store(v, &dst[p]);
        }
    }
}

extern "C" void kernel_launch(void* const* d_in, const int* in_sizes, int n_in,
                              void* d_out, int out_size, void* d_ws, size_t ws_size,
                              hipStream_t stream) {
    const vfloat4* in  = (const vfloat4*)d_in[0];   // [256,128,64] fp32
    vfloat4*       out = (vfloat4*)d_out;           // [256,16256,64] fp32

    const int grid = 256 * NNODES;                  // one block per (b, node)
    NodeEdgeProjection_5025111736904_kernel<<<grid, BLOCK, 0, stream>>>(in, out);
}